// Round 13
// baseline (340.615 us; speedup 1.0000x reference)
//
#include <hip/hip_runtime.h>
#include <hip/hip_fp16.h>
#include <stdint.h>

#define NNODES 100000
#define NEDGES 1600000
#define DINPUT 128
#define DH 64
#define NELEM (NNODES * DH)   // 6,400,000
#define CAP 48                // padded row capacity (Poisson(16): P(deg>=48) ~ 5e-11)
#define SCAN_B 1024
#define SCAN_NB ((NNODES + SCAN_B - 1) / SCAN_B)   // 98

#define G_GEMM (NNODES / 32)          // 3125 (exact)
#define G_EDGE (NEDGES / 256)         // 6250 (exact) == 2*G_GEMM
#define G_GATH (NNODES / 16)          // 6250 (exact)

// ---------------- threefry2x32-20 (exact JAX implementation) ----------------
__host__ __device__ __forceinline__ void tf2x32(uint32_t k0, uint32_t k1,
                                                uint32_t x0, uint32_t x1,
                                                uint32_t* o0, uint32_t* o1) {
  uint32_t k2 = k0 ^ k1 ^ 0x1BD11BDAu;
  x0 += k0; x1 += k1;
#define TF_ROT(r) { x0 += x1; x1 = (x1 << (r)) | (x1 >> (32 - (r))); x1 ^= x0; }
  TF_ROT(13) TF_ROT(15) TF_ROT(26) TF_ROT(6)
  x0 += k1; x1 += k2 + 1u;
  TF_ROT(17) TF_ROT(29) TF_ROT(16) TF_ROT(24)
  x0 += k2; x1 += k0 + 2u;
  TF_ROT(13) TF_ROT(15) TF_ROT(26) TF_ROT(6)
  x0 += k0; x1 += k1 + 3u;
  TF_ROT(17) TF_ROT(29) TF_ROT(16) TF_ROT(24)
  x0 += k1; x1 += k2 + 4u;
  TF_ROT(13) TF_ROT(15) TF_ROT(26) TF_ROT(6)
  x0 += k2; x1 += k0 + 5u;
#undef TF_ROT
  *o0 = x0; *o1 = x1;
}

// ---- fp16 row helpers: 4 dims per lane as int2 (2x half2) ----
__device__ __forceinline__ float4 h4_load(const int2* hp, size_t idx) {
  int2 r = hp[idx];
  __half2 a = *reinterpret_cast<__half2*>(&r.x);
  __half2 b = *reinterpret_cast<__half2*>(&r.y);
  float2 fa = __half22float2(a);
  float2 fb = __half22float2(b);
  return float4{fa.x, fa.y, fb.x, fb.y};
}
__device__ __forceinline__ int2 h4_pack(float4 v) {
  __half2 a = __floats2half2_rn(v.x, v.y);
  __half2 b = __floats2half2_rn(v.z, v.w);
  int2 r;
  r.x = *reinterpret_cast<int*>(&a);
  r.y = *reinterpret_cast<int*>(&b);
  return r;
}

// ---------------- cnt = 0 ----------------
__global__ void k_zero(int* cnt) {
  int n = blockIdx.x * 256 + threadIdx.x;
  if (n < NNODES) cnt[n] = 0;
}

// ======== FUSED: direct bucket fill (1 atomic/edge)  +  layer-1 GEMM ========
// Grid = 3*G_GEMM. Roles: bid%3==2 -> GEMM block (bid/3); else fill block
// f = (bid/3)*2 + bid%3 (covers [0, G_EDGE) exactly).
// gemm_only=1: grid = G_GEMM, every block is a GEMM block (compact fallback).
// Fill stores are NONTEMPORAL (r10: 112->103us; cpair thrashes L2, NT skips RFO).
// Fill time is occupancy-insensitive (r5 vs r8) => chip atomic-throughput floor.
__global__ __launch_bounds__(256) void k_fill_gemm(
    const int* __restrict__ src, const int* __restrict__ dst,
    const float* __restrict__ w, int* cnt, int2* __restrict__ cp,
    const float* __restrict__ x, const float* __restrict__ W1,
    __half* __restrict__ B, int gemm_only) {
  __shared__ float Wt[DH][DINPUT + 4];          // transposed W1, padded
  __shared__ float4 rows4[32][DINPUT / 4];
  int t = threadIdx.x;
  int bid = blockIdx.x;
  int g, r;
  if (gemm_only) { g = bid; r = 2; } else { g = bid / 3; r = bid % 3; }
  if (r == 2) {
    // ---- GEMM role: B[N,64] = fp16(x[N,128] @ W1[128,64]); 32 rows/block ----
    for (int i = t; i < DINPUT * DH; i += 256) {
      int k = i >> 6, d = i & 63;
      Wt[d][k] = W1[i];
    }
    int n0 = g * 32;
    const float4* hv = (const float4*)x;
    for (int i = t; i < 32 * (DINPUT / 4); i += 256) {
      int rr = i >> 5, kk = i & 31;
      rows4[rr][kk] = hv[(size_t)(n0 + rr) * (DINPUT / 4) + kk];
    }
    __syncthreads();
    int d = t & 63;
    int wv = t >> 6;
    float acc[8] = {0.f, 0.f, 0.f, 0.f, 0.f, 0.f, 0.f, 0.f};
    const float4* wt4 = (const float4*)&Wt[d][0];
#pragma unroll 4
    for (int kq = 0; kq < DINPUT / 4; ++kq) {
      float4 wq = wt4[kq];
#pragma unroll
      for (int rr = 0; rr < 8; ++rr) {
        float4 hq = rows4[wv * 8 + rr][kq];
        acc[rr] += hq.x * wq.x + hq.y * wq.y + hq.z * wq.z + hq.w * wq.w;
      }
    }
#pragma unroll
    for (int rr = 0; rr < 8; ++rr)
      B[(size_t)(n0 + wv * 8 + rr) * DH + d] = __float2half_rn(acc[rr]);
  } else {
    // ---- fill role: 1 edge/thread, 1 atomic slot claim, NT store ----
    int f = g * 2 + r;
    int e = f * 256 + t;
    int s  = __builtin_nontemporal_load(src + e);
    int d  = __builtin_nontemporal_load(dst + e);
    float wv = __builtin_nontemporal_load(w + e);
    int slot = atomicAdd(&cnt[d], 1);
    if (slot < CAP) {
      long long pv = ((long long)__float_as_int(wv) << 32) | (unsigned)s;
      __builtin_nontemporal_store(pv, (long long*)(cp + (size_t)d * CAP + slot));
    }
  }
}

// ======== COMPACT fallback path (ws too small): hist + scan + fill ========
__global__ void k_hist(const int* __restrict__ dst, int* cnt) {
  int e = blockIdx.x * 256 + threadIdx.x;
  if (e < NEDGES) atomicAdd(&cnt[dst[e]], 1);
}

__global__ __launch_bounds__(1024) void k_scan1(const int* __restrict__ cnt,
                                                int* __restrict__ lpre,
                                                int* __restrict__ bsum) {
  __shared__ int ps[SCAN_B];
  int t = threadIdx.x;
  int n = blockIdx.x * SCAN_B + t;
  int v = (n < NNODES) ? cnt[n] : 0;
  ps[t] = v;
  __syncthreads();
  for (int off = 1; off < SCAN_B; off <<= 1) {
    int u = (t >= off) ? ps[t - off] : 0;
    __syncthreads();
    ps[t] += u;
    __syncthreads();
  }
  if (n < NNODES) lpre[n] = ps[t] - v;
  if (t == SCAN_B - 1) bsum[blockIdx.x] = ps[t];
}

__global__ __launch_bounds__(128) void k_scan2(int* bsum) {
  __shared__ int ps[128];
  int t = threadIdx.x;
  int v = (t < SCAN_NB) ? bsum[t] : 0;
  ps[t] = v;
  __syncthreads();
  for (int off = 1; off < 128; off <<= 1) {
    int u = (t >= off) ? ps[t - off] : 0;
    __syncthreads();
    ps[t] += u;
    __syncthreads();
  }
  if (t < SCAN_NB) bsum[t] = ps[t] - v;
}

__global__ __launch_bounds__(1024) void k_scan3(const int* __restrict__ bsum,
                                                int* __restrict__ lpre_rowptr,
                                                int* __restrict__ wptr) {
  int t = threadIdx.x;
  int n = blockIdx.x * SCAN_B + t;
  if (n < NNODES) {
    int r = lpre_rowptr[n] + bsum[blockIdx.x];
    lpre_rowptr[n] = r;
    wptr[n] = r;
  }
  if (n == 0) lpre_rowptr[NNODES] = NEDGES;
}

__global__ void k_fill_compact(const int* __restrict__ src, const int* __restrict__ dst,
                               const float* __restrict__ w, int* wptr,
                               int2* __restrict__ cp) {
  int e = blockIdx.x * 256 + threadIdx.x;
  if (e < NEDGES) {
    int s = src[e], d = dst[e];
    int slot = atomicAdd(&wptr[d], 1);
    cp[slot] = int2{s, __float_as_int(w[e])};
  }
}

// ------- deg[n] = 1 + row-sum(w) -> dinv; 16 lanes per row, shfl reduce -------
template <int PADDED>
__global__ __launch_bounds__(256) void k_degrow(const int* __restrict__ rowptr,
                                                const int* __restrict__ cnt,
                                                const int2* __restrict__ cp,
                                                float* __restrict__ dinv) {
  int g = blockIdx.x * 16 + (threadIdx.x >> 4);
  int sl = threadIdx.x & 15;
  int beg = PADDED ? g * CAP : rowptr[g];
  int num = PADDED ? min(cnt[g], CAP) : rowptr[g + 1] - beg;
  const long long* cp8 = (const long long*)cp;
  float s = 0.0f;
  for (int i = sl; i < num; i += 16) {
    long long q = __builtin_nontemporal_load(cp8 + beg + i);
    s += __int_as_float((int)(q >> 32));
  }
  s += __shfl_xor(s, 1);
  s += __shfl_xor(s, 2);
  s += __shfl_xor(s, 4);
  s += __shfl_xor(s, 8);
  if (sl == 0) dinv[g] = 1.0f / sqrtf(1.0f + s);
}

// ==== FUSED gather + scale + bias + ELU + dropout + {next-layer GEMM | lin} ====
// h2 rows are fp16 (64 x half = 128B). 16 lanes/node, int2 (8B) NT loads for
// cpair (streamed once; keep L2 for h2 rows). Edge loop is fully batched:
// last batch padded to 8 with slot=beg / weight=0 (no serial tail).
// MODE=0: phase 2 h @ Wn -> fp16 outp[N,64]. MODE=1: h.lw+lb -> fp32 outp[N].
template <int MODE, int PADDED>
__global__ __launch_bounds__(256) void k_gg(
    const __half* __restrict__ h2, const int* __restrict__ rowptr,
    const int* __restrict__ cnt, const int2* __restrict__ cpair,
    const float* __restrict__ dinv, const float* __restrict__ bias,
    const float* __restrict__ Wn, const float* __restrict__ lw,
    const float* __restrict__ lb, void* __restrict__ outp,
    uint32_t k0, uint32_t k1) {
  __shared__ float4 Ws4[DH * 16];      // W[d][d'] as float4 over d'   (16 KB)
  __shared__ float4 hs4[16 * 17];      // h rows, stride 17 (bank-spread)
  int t = threadIdx.x;
  int g = blockIdx.x * 16 + (t >> 4);  // grid covers exactly NNODES
  int sl = t & 15;
  int n = t >> 4;
  const int2* h4 = (const int2*)h2;    // 4 fp16 dims per int2
  const long long* cp8 = (const long long*)cpair;

  if (MODE == 0) {
    const float4* wv = (const float4*)Wn;
    for (int i = t; i < DH * 16; i += 256) Ws4[i] = wv[i];
  }

  float dg = dinv[g];
  float4 self = h4_load(h4, (size_t)g * 16 + sl);
  float4 acc = {0.f, 0.f, 0.f, 0.f};

  int beg = PADDED ? g * CAP : rowptr[g];
  int end = beg + (PADDED ? min(cnt[g], CAP) : rowptr[g + 1] - beg);

  for (int e = beg; e < end; e += 8) {
    long long q[8];
#pragma unroll
    for (int j = 0; j < 8; ++j) {
      int ix = (e + j < end) ? (e + j) : beg;   // pad with valid slot
      q[j] = __builtin_nontemporal_load(cp8 + ix);
    }
    int sidx[8];
    float wgt[8];
#pragma unroll
    for (int j = 0; j < 8; ++j) {
      sidx[j] = (int)(unsigned)q[j];
      float val = __int_as_float((int)(q[j] >> 32));
      wgt[j] = (e + j < end) ? dinv[sidx[j]] * val : 0.0f;
    }
#pragma unroll
    for (int j = 0; j < 8; ++j) {
      float4 v = h4_load(h4, (size_t)sidx[j] * 16 + sl);
      acc.x += v.x * wgt[j];
      acc.y += v.y * wgt[j];
      acc.z += v.z * wgt[j];
      acc.w += v.w * wgt[j];
    }
  }

  const float4 bv = ((const float4*)bias)[sl];
  acc.x = dg * (acc.x + dg * self.x) + bv.x;
  acc.y = dg * (acc.y + dg * self.y) + bv.y;
  acc.z = dg * (acc.z + dg * self.z) + bv.z;
  acc.w = dg * (acc.w + dg * self.w) + bv.w;

  // ELU
  acc.x = (acc.x > 0.0f) ? acc.x : expm1f(acc.x);
  acc.y = (acc.y > 0.0f) ? acc.y : expm1f(acc.y);
  acc.z = (acc.z > 0.0f) ? acc.z : expm1f(acc.z);
  acc.w = (acc.w > 0.0f) ? acc.w : expm1f(acc.w);

  // dropout (JAX threefry partitionable): bits[i]=o0^o1 of tf(dk,(0,i))
  uint32_t base = (uint32_t)g * 64u + (uint32_t)sl * 4u;
  uint32_t o0, o1;
  tf2x32(k0, k1, 0u, base + 0u, &o0, &o1);
  acc.x = (((o0 ^ o1) >> 31) == 0u) ? 2.0f * acc.x : 0.0f;
  tf2x32(k0, k1, 0u, base + 1u, &o0, &o1);
  acc.y = (((o0 ^ o1) >> 31) == 0u) ? 2.0f * acc.y : 0.0f;
  tf2x32(k0, k1, 0u, base + 2u, &o0, &o1);
  acc.z = (((o0 ^ o1) >> 31) == 0u) ? 2.0f * acc.z : 0.0f;
  tf2x32(k0, k1, 0u, base + 3u, &o0, &o1);
  acc.w = (((o0 ^ o1) >> 31) == 0u) ? 2.0f * acc.w : 0.0f;

  if (MODE == 1) {
    const float4 lv = ((const float4*)lw)[sl];
    float dot = acc.x * lv.x + acc.y * lv.y + acc.z * lv.z + acc.w * lv.w;
    dot += __shfl_xor(dot, 1);
    dot += __shfl_xor(dot, 2);
    dot += __shfl_xor(dot, 4);
    dot += __shfl_xor(dot, 8);
    if (sl == 0) ((float*)outp)[g] = dot + lb[0];
  } else {
    // ---- phase 2: out[g][:] = fp16(h[g][:] @ Wn) ----
    hs4[n * 17 + sl] = acc;
    __syncthreads();
    float4 o = {0.f, 0.f, 0.f, 0.f};
#pragma unroll
    for (int dq = 0; dq < 16; ++dq) {
      float4 hq = hs4[n * 17 + dq];
      float4 w0 = Ws4[(dq * 4 + 0) * 16 + sl];
      float4 w1 = Ws4[(dq * 4 + 1) * 16 + sl];
      float4 w2 = Ws4[(dq * 4 + 2) * 16 + sl];
      float4 w3 = Ws4[(dq * 4 + 3) * 16 + sl];
      o.x += hq.x * w0.x + hq.y * w1.x + hq.z * w2.x + hq.w * w3.x;
      o.y += hq.x * w0.y + hq.y * w1.y + hq.z * w2.y + hq.w * w3.y;
      o.z += hq.x * w0.z + hq.y * w1.z + hq.z * w2.z + hq.w * w3.z;
      o.w += hq.x * w0.w + hq.y * w1.w + hq.z * w2.w + hq.w * w3.w;
    }
    ((int2*)outp)[(size_t)g * 16 + sl] = h4_pack(o);
  }
}

extern "C" void kernel_launch(void* const* d_in, const int* in_sizes, int n_in,
                              void* d_out, int out_size, void* d_ws, size_t ws_size,
                              hipStream_t stream) {
  const float* x   = (const float*)d_in[0];
  const int*   ei  = (const int*)d_in[1];
  const float* ew  = (const float*)d_in[2];
  const float* W1  = (const float*)d_in[3];
  const float* b1  = (const float*)d_in[4];
  const float* Wh  = (const float*)d_in[5];
  const float* bh  = (const float*)d_in[6];
  const float* lw  = (const float*)d_in[7];
  const float* lb  = (const float*)d_in[8];
  float* out = (float*)d_out;

  const int* src = ei;            // edge_index[0] (message sources)
  const int* dst = ei + NEDGES;   // edge_index[1] (aggregation targets)

  // --- workspace layout; padded CSR if ws allows, else compact fallback ---
  const size_t capE = (size_t)NNODES * CAP;        // 4.8M padded slots
  const size_t needPadded =
      (size_t)NELEM * 2 * 2 + capE * 8 +
      ((size_t)NNODES * 3 + 1 + SCAN_NB) * 4;      // ~65 MB
  const bool padded = ws_size >= needPadded;
  const size_t nSlots = padded ? capE : (size_t)NEDGES;

  __half* A     = (__half*)d_ws;                     // N*64 fp16 (12.8 MB)
  __half* B     = A + (size_t)NELEM;                 // N*64 fp16 (12.8 MB)
  int2*  cpair  = (int2*)(B + (size_t)NELEM);        // padded: N*CAP, compact: E
  float* dinv   = (float*)(cpair + nSlots);          // N
  int*   cnt    = (int*)(dinv + (size_t)NNODES);     // N
  int*   rowptr = cnt + (size_t)NNODES;              // N+1 (compact only)
  int*   wptr   = rowptr + (size_t)NNODES + 1;       // N   (compact only)
  int*   bsum   = wptr + (size_t)NNODES;             // SCAN_NB (compact only)

  // dropout keys = jax.random.split(jax.random.key(42), 3), partitionable
  uint32_t dk[3][2];
  for (uint32_t i = 0; i < 3; ++i) tf2x32(0u, 42u, 0u, i, &dk[i][0], &dk[i][1]);

  const int gN = (NNODES + 255) / 256;
  const float* Wh0 = Wh;
  const float* Wh1 = Wh + (size_t)DH * DH;

  if (padded) {
    k_zero<<<gN, 256, 0, stream>>>(cnt);
    // 9375 blocks: 3125 GEMM (bid%3==2) + 6250 fill (bid%3 in {0,1})
    k_fill_gemm<<<3 * G_GEMM, 256, 0, stream>>>(src, dst, ew, cnt, cpair,
                                                x, W1, B, 0);
    k_degrow<1><<<G_GATH, 256, 0, stream>>>(rowptr, cnt, cpair, dinv);

    k_gg<0, 1><<<G_GATH, 256, 0, stream>>>(B, rowptr, cnt, cpair, dinv, b1,
                                           Wh0, lw, lb, A, dk[0][0], dk[0][1]);
    k_gg<0, 1><<<G_GATH, 256, 0, stream>>>(A, rowptr, cnt, cpair, dinv, bh,
                                           Wh1, lw, lb, B, dk[1][0], dk[1][1]);
    k_gg<1, 1><<<G_GATH, 256, 0, stream>>>(B, rowptr, cnt, cpair, dinv, bh + DH,
                                           nullptr, lw, lb, out, dk[2][0], dk[2][1]);
  } else {
    k_zero<<<gN, 256, 0, stream>>>(cnt);
    k_hist<<<G_EDGE, 256, 0, stream>>>(dst, cnt);
    k_scan1<<<SCAN_NB, SCAN_B, 0, stream>>>(cnt, rowptr, bsum);
    k_scan2<<<1, 128, 0, stream>>>(bsum);
    k_scan3<<<SCAN_NB, SCAN_B, 0, stream>>>(bsum, rowptr, wptr);
    k_fill_compact<<<G_EDGE, 256, 0, stream>>>(src, dst, ew, wptr, cpair);
    k_degrow<0><<<G_GATH, 256, 0, stream>>>(rowptr, cnt, cpair, dinv);
    k_fill_gemm<<<G_GEMM, 256, 0, stream>>>(src, dst, ew, cnt, nullptr,
                                            x, W1, B, 1);   // GEMM-only

    k_gg<0, 0><<<G_GATH, 256, 0, stream>>>(B, rowptr, cnt, cpair, dinv, b1,
                                           Wh0, lw, lb, A, dk[0][0], dk[0][1]);
    k_gg<0, 0><<<G_GATH, 256, 0, stream>>>(A, rowptr, cnt, cpair, dinv, bh,
                                           Wh1, lw, lb, B, dk[1][0], dk[1][1]);
    k_gg<1, 0><<<G_GATH, 256, 0, stream>>>(B, rowptr, cnt, cpair, dinv, bh + DH,
                                           nullptr, lw, lb, out, dk[2][0], dk[2][1]);
  }
}

// Round 14
// 268.514 us; speedup vs baseline: 1.2685x; 1.2685x over previous
//
#include <hip/hip_runtime.h>
#include <hip/hip_fp16.h>
#include <stdint.h>

#define NNODES 100000
#define NEDGES 1600000
#define DINPUT 128
#define DH 64
#define NELEM (NNODES * DH)   // 6,400,000
#define CAP 48                // padded row capacity (Poisson(16): P(deg>=48) ~ 5e-11)
#define SCAN_B 1024
#define SCAN_NB ((NNODES + SCAN_B - 1) / SCAN_B)   // 98

#define G_GEMM (NNODES / 32)          // 3125 (exact)
#define G_EDGE (NEDGES / 256)         // 6250 (exact) == 2*G_GEMM
#define G_GATH (NNODES / 16)          // 6250 (exact)

// ---------------- threefry2x32-20 (exact JAX implementation) ----------------
__host__ __device__ __forceinline__ void tf2x32(uint32_t k0, uint32_t k1,
                                                uint32_t x0, uint32_t x1,
                                                uint32_t* o0, uint32_t* o1) {
  uint32_t k2 = k0 ^ k1 ^ 0x1BD11BDAu;
  x0 += k0; x1 += k1;
#define TF_ROT(r) { x0 += x1; x1 = (x1 << (r)) | (x1 >> (32 - (r))); x1 ^= x0; }
  TF_ROT(13) TF_ROT(15) TF_ROT(26) TF_ROT(6)
  x0 += k1; x1 += k2 + 1u;
  TF_ROT(17) TF_ROT(29) TF_ROT(16) TF_ROT(24)
  x0 += k2; x1 += k0 + 2u;
  TF_ROT(13) TF_ROT(15) TF_ROT(26) TF_ROT(6)
  x0 += k0; x1 += k1 + 3u;
  TF_ROT(17) TF_ROT(29) TF_ROT(16) TF_ROT(24)
  x0 += k1; x1 += k2 + 4u;
  TF_ROT(13) TF_ROT(15) TF_ROT(26) TF_ROT(6)
  x0 += k2; x1 += k0 + 5u;
#undef TF_ROT
  *o0 = x0; *o1 = x1;
}

// ---- fp16 row helpers: 4 dims per lane as int2 (2x half2) ----
__device__ __forceinline__ float4 h4_load(const int2* hp, size_t idx) {
  int2 r = hp[idx];
  __half2 a = *reinterpret_cast<__half2*>(&r.x);
  __half2 b = *reinterpret_cast<__half2*>(&r.y);
  float2 fa = __half22float2(a);
  float2 fb = __half22float2(b);
  return float4{fa.x, fa.y, fb.x, fb.y};
}
__device__ __forceinline__ int2 h4_pack(float4 v) {
  __half2 a = __floats2half2_rn(v.x, v.y);
  __half2 b = __floats2half2_rn(v.z, v.w);
  int2 r;
  r.x = *reinterpret_cast<int*>(&a);
  r.y = *reinterpret_cast<int*>(&b);
  return r;
}

// ---------------- cnt = 0 ----------------
__global__ void k_zero(int* cnt) {
  int n = blockIdx.x * 256 + threadIdx.x;
  if (n < NNODES) cnt[n] = 0;
}

// ======== FUSED: direct bucket fill (1 atomic/edge)  +  layer-1 GEMM ========
// Grid = 3*G_GEMM. Roles: bid%3==2 -> GEMM block (bid/3); else fill block
// f = (bid/3)*2 + bid%3 (covers [0, G_EDGE) exactly).
// gemm_only=1: grid = G_GEMM, every block is a GEMM block (compact fallback).
// Fill stores are NONTEMPORAL (r10: 112->103us; cpair thrashes L2, NT skips RFO).
// Fill time is occupancy-insensitive (r5 vs r8) => chip atomic-throughput floor.
__global__ __launch_bounds__(256) void k_fill_gemm(
    const int* __restrict__ src, const int* __restrict__ dst,
    const float* __restrict__ w, int* cnt, int2* __restrict__ cp,
    const float* __restrict__ x, const float* __restrict__ W1,
    __half* __restrict__ B, int gemm_only) {
  __shared__ float Wt[DH][DINPUT + 4];          // transposed W1, padded
  __shared__ float4 rows4[32][DINPUT / 4];
  int t = threadIdx.x;
  int bid = blockIdx.x;
  int g, r;
  if (gemm_only) { g = bid; r = 2; } else { g = bid / 3; r = bid % 3; }
  if (r == 2) {
    // ---- GEMM role: B[N,64] = fp16(x[N,128] @ W1[128,64]); 32 rows/block ----
    for (int i = t; i < DINPUT * DH; i += 256) {
      int k = i >> 6, d = i & 63;
      Wt[d][k] = W1[i];
    }
    int n0 = g * 32;
    const float4* hv = (const float4*)x;
    for (int i = t; i < 32 * (DINPUT / 4); i += 256) {
      int rr = i >> 5, kk = i & 31;
      rows4[rr][kk] = hv[(size_t)(n0 + rr) * (DINPUT / 4) + kk];
    }
    __syncthreads();
    int d = t & 63;
    int wv = t >> 6;
    float acc[8] = {0.f, 0.f, 0.f, 0.f, 0.f, 0.f, 0.f, 0.f};
    const float4* wt4 = (const float4*)&Wt[d][0];
#pragma unroll 4
    for (int kq = 0; kq < DINPUT / 4; ++kq) {
      float4 wq = wt4[kq];
#pragma unroll
      for (int rr = 0; rr < 8; ++rr) {
        float4 hq = rows4[wv * 8 + rr][kq];
        acc[rr] += hq.x * wq.x + hq.y * wq.y + hq.z * wq.z + hq.w * wq.w;
      }
    }
#pragma unroll
    for (int rr = 0; rr < 8; ++rr)
      B[(size_t)(n0 + wv * 8 + rr) * DH + d] = __float2half_rn(acc[rr]);
  } else {
    // ---- fill role: 1 edge/thread, 1 atomic slot claim, NT store ----
    int f = g * 2 + r;
    int e = f * 256 + t;
    int s  = __builtin_nontemporal_load(src + e);
    int d  = __builtin_nontemporal_load(dst + e);
    float wv = __builtin_nontemporal_load(w + e);
    int slot = atomicAdd(&cnt[d], 1);
    if (slot < CAP) {
      long long pv = ((long long)__float_as_int(wv) << 32) | (unsigned)s;
      __builtin_nontemporal_store(pv, (long long*)(cp + (size_t)d * CAP + slot));
    }
  }
}

// ======== COMPACT fallback path (ws too small): hist + scan + fill ========
__global__ void k_hist(const int* __restrict__ dst, int* cnt) {
  int e = blockIdx.x * 256 + threadIdx.x;
  if (e < NEDGES) atomicAdd(&cnt[dst[e]], 1);
}

__global__ __launch_bounds__(1024) void k_scan1(const int* __restrict__ cnt,
                                                int* __restrict__ lpre,
                                                int* __restrict__ bsum) {
  __shared__ int ps[SCAN_B];
  int t = threadIdx.x;
  int n = blockIdx.x * SCAN_B + t;
  int v = (n < NNODES) ? cnt[n] : 0;
  ps[t] = v;
  __syncthreads();
  for (int off = 1; off < SCAN_B; off <<= 1) {
    int u = (t >= off) ? ps[t - off] : 0;
    __syncthreads();
    ps[t] += u;
    __syncthreads();
  }
  if (n < NNODES) lpre[n] = ps[t] - v;
  if (t == SCAN_B - 1) bsum[blockIdx.x] = ps[t];
}

__global__ __launch_bounds__(128) void k_scan2(int* bsum) {
  __shared__ int ps[128];
  int t = threadIdx.x;
  int v = (t < SCAN_NB) ? bsum[t] : 0;
  ps[t] = v;
  __syncthreads();
  for (int off = 1; off < 128; off <<= 1) {
    int u = (t >= off) ? ps[t - off] : 0;
    __syncthreads();
    ps[t] += u;
    __syncthreads();
  }
  if (t < SCAN_NB) bsum[t] = ps[t] - v;
}

__global__ __launch_bounds__(1024) void k_scan3(const int* __restrict__ bsum,
                                                int* __restrict__ lpre_rowptr,
                                                int* __restrict__ wptr) {
  int t = threadIdx.x;
  int n = blockIdx.x * SCAN_B + t;
  if (n < NNODES) {
    int r = lpre_rowptr[n] + bsum[blockIdx.x];
    lpre_rowptr[n] = r;
    wptr[n] = r;
  }
  if (n == 0) lpre_rowptr[NNODES] = NEDGES;
}

__global__ void k_fill_compact(const int* __restrict__ src, const int* __restrict__ dst,
                               const float* __restrict__ w, int* wptr,
                               int2* __restrict__ cp) {
  int e = blockIdx.x * 256 + threadIdx.x;
  if (e < NEDGES) {
    int s = src[e], d = dst[e];
    int slot = atomicAdd(&wptr[d], 1);
    cp[slot] = int2{s, __float_as_int(w[e])};
  }
}

// ------- deg[n] = 1 + row-sum(w) -> dinv; 16 lanes per row, shfl reduce -------
template <int PADDED>
__global__ __launch_bounds__(256) void k_degrow(const int* __restrict__ rowptr,
                                                const int* __restrict__ cnt,
                                                const int2* __restrict__ cp,
                                                float* __restrict__ dinv) {
  int g = blockIdx.x * 16 + (threadIdx.x >> 4);
  int sl = threadIdx.x & 15;
  int beg = PADDED ? g * CAP : rowptr[g];
  int num = PADDED ? min(cnt[g], CAP) : rowptr[g + 1] - beg;
  float s = 0.0f;
  for (int i = sl; i < num; i += 16) s += __int_as_float(cp[beg + i].y);
  s += __shfl_xor(s, 1);
  s += __shfl_xor(s, 2);
  s += __shfl_xor(s, 4);
  s += __shfl_xor(s, 8);
  if (sl == 0) dinv[g] = 1.0f / sqrtf(1.0f + s);
}

// ==== FUSED gather + scale + bias + ELU + dropout + {next-layer GEMM | lin} ====
// h2 rows are fp16 (64 x half = 128B). 16 lanes/node, int2 (8B) loads, 8-deep
// pipeline + scalar tail (r12 configuration — known good; masked-pad tail and
// NT cpair loads both regressed in r13, int4/8-lane regressed in r11).
// MODE=0: phase 2 h @ Wn -> fp16 outp[N,64]. MODE=1: h.lw+lb -> fp32 outp[N].
template <int MODE, int PADDED>
__global__ __launch_bounds__(256) void k_gg(
    const __half* __restrict__ h2, const int* __restrict__ rowptr,
    const int* __restrict__ cnt, const int2* __restrict__ cpair,
    const float* __restrict__ dinv, const float* __restrict__ bias,
    const float* __restrict__ Wn, const float* __restrict__ lw,
    const float* __restrict__ lb, void* __restrict__ outp,
    uint32_t k0, uint32_t k1) {
  __shared__ float4 Ws4[DH * 16];      // W[d][d'] as float4 over d'   (16 KB)
  __shared__ float4 hs4[16 * 17];      // h rows, stride 17 (bank-spread)
  int t = threadIdx.x;
  int g = blockIdx.x * 16 + (t >> 4);  // grid covers exactly NNODES
  int sl = t & 15;
  int n = t >> 4;
  const int2* h4 = (const int2*)h2;    // 4 fp16 dims per int2

  if (MODE == 0) {
    const float4* wv = (const float4*)Wn;
    for (int i = t; i < DH * 16; i += 256) Ws4[i] = wv[i];
  }

  float dg = dinv[g];
  float4 self = h4_load(h4, (size_t)g * 16 + sl);
  float4 acc = {0.f, 0.f, 0.f, 0.f};

  int beg = PADDED ? g * CAP : rowptr[g];
  int end = beg + (PADDED ? min(cnt[g], CAP) : rowptr[g + 1] - beg);

  int e = beg;
  for (; e + 8 <= end; e += 8) {
    int2 p0 = cpair[e + 0], p1 = cpair[e + 1], p2 = cpair[e + 2], p3 = cpair[e + 3];
    int2 p4 = cpair[e + 4], p5 = cpair[e + 5], p6 = cpair[e + 6], p7 = cpair[e + 7];
    float d0 = dinv[p0.x], d1 = dinv[p1.x], d2 = dinv[p2.x], d3 = dinv[p3.x];
    float d4 = dinv[p4.x], d5 = dinv[p5.x], d6 = dinv[p6.x], d7 = dinv[p7.x];
    float4 v0 = h4_load(h4, (size_t)p0.x * 16 + sl);
    float4 v1 = h4_load(h4, (size_t)p1.x * 16 + sl);
    float4 v2 = h4_load(h4, (size_t)p2.x * 16 + sl);
    float4 v3 = h4_load(h4, (size_t)p3.x * 16 + sl);
    float4 v4 = h4_load(h4, (size_t)p4.x * 16 + sl);
    float4 v5 = h4_load(h4, (size_t)p5.x * 16 + sl);
    float4 v6 = h4_load(h4, (size_t)p6.x * 16 + sl);
    float4 v7 = h4_load(h4, (size_t)p7.x * 16 + sl);
    float w0 = d0 * __int_as_float(p0.y), w1 = d1 * __int_as_float(p1.y);
    float w2 = d2 * __int_as_float(p2.y), w3 = d3 * __int_as_float(p3.y);
    float w4 = d4 * __int_as_float(p4.y), w5 = d5 * __int_as_float(p5.y);
    float w6 = d6 * __int_as_float(p6.y), w7 = d7 * __int_as_float(p7.y);
    acc.x += v0.x * w0 + v1.x * w1 + v2.x * w2 + v3.x * w3
           + v4.x * w4 + v5.x * w5 + v6.x * w6 + v7.x * w7;
    acc.y += v0.y * w0 + v1.y * w1 + v2.y * w2 + v3.y * w3
           + v4.y * w4 + v5.y * w5 + v6.y * w6 + v7.y * w7;
    acc.z += v0.z * w0 + v1.z * w1 + v2.z * w2 + v3.z * w3
           + v4.z * w4 + v5.z * w5 + v6.z * w6 + v7.z * w7;
    acc.w += v0.w * w0 + v1.w * w1 + v2.w * w2 + v3.w * w3
           + v4.w * w4 + v5.w * w5 + v6.w * w6 + v7.w * w7;
  }
  for (; e < end; ++e) {
    int2 p = cpair[e];
    float nm = dinv[p.x] * __int_as_float(p.y);
    float4 v = h4_load(h4, (size_t)p.x * 16 + sl);
    acc.x += v.x * nm;
    acc.y += v.y * nm;
    acc.z += v.z * nm;
    acc.w += v.w * nm;
  }

  const float4 bv = ((const float4*)bias)[sl];
  acc.x = dg * (acc.x + dg * self.x) + bv.x;
  acc.y = dg * (acc.y + dg * self.y) + bv.y;
  acc.z = dg * (acc.z + dg * self.z) + bv.z;
  acc.w = dg * (acc.w + dg * self.w) + bv.w;

  // ELU
  acc.x = (acc.x > 0.0f) ? acc.x : expm1f(acc.x);
  acc.y = (acc.y > 0.0f) ? acc.y : expm1f(acc.y);
  acc.z = (acc.z > 0.0f) ? acc.z : expm1f(acc.z);
  acc.w = (acc.w > 0.0f) ? acc.w : expm1f(acc.w);

  // dropout (JAX threefry partitionable): bits[i]=o0^o1 of tf(dk,(0,i))
  uint32_t base = (uint32_t)g * 64u + (uint32_t)sl * 4u;
  uint32_t o0, o1;
  tf2x32(k0, k1, 0u, base + 0u, &o0, &o1);
  acc.x = (((o0 ^ o1) >> 31) == 0u) ? 2.0f * acc.x : 0.0f;
  tf2x32(k0, k1, 0u, base + 1u, &o0, &o1);
  acc.y = (((o0 ^ o1) >> 31) == 0u) ? 2.0f * acc.y : 0.0f;
  tf2x32(k0, k1, 0u, base + 2u, &o0, &o1);
  acc.z = (((o0 ^ o1) >> 31) == 0u) ? 2.0f * acc.z : 0.0f;
  tf2x32(k0, k1, 0u, base + 3u, &o0, &o1);
  acc.w = (((o0 ^ o1) >> 31) == 0u) ? 2.0f * acc.w : 0.0f;

  if (MODE == 1) {
    const float4 lv = ((const float4*)lw)[sl];
    float dot = acc.x * lv.x + acc.y * lv.y + acc.z * lv.z + acc.w * lv.w;
    dot += __shfl_xor(dot, 1);
    dot += __shfl_xor(dot, 2);
    dot += __shfl_xor(dot, 4);
    dot += __shfl_xor(dot, 8);
    if (sl == 0) ((float*)outp)[g] = dot + lb[0];
  } else {
    // ---- phase 2: out[g][:] = fp16(h[g][:] @ Wn) ----
    hs4[n * 17 + sl] = acc;
    __syncthreads();
    float4 o = {0.f, 0.f, 0.f, 0.f};
#pragma unroll
    for (int dq = 0; dq < 16; ++dq) {
      float4 hq = hs4[n * 17 + dq];
      float4 w0 = Ws4[(dq * 4 + 0) * 16 + sl];
      float4 w1 = Ws4[(dq * 4 + 1) * 16 + sl];
      float4 w2 = Ws4[(dq * 4 + 2) * 16 + sl];
      float4 w3 = Ws4[(dq * 4 + 3) * 16 + sl];
      o.x += hq.x * w0.x + hq.y * w1.x + hq.z * w2.x + hq.w * w3.x;
      o.y += hq.x * w0.y + hq.y * w1.y + hq.z * w2.y + hq.w * w3.y;
      o.z += hq.x * w0.z + hq.y * w1.z + hq.z * w2.z + hq.w * w3.z;
      o.w += hq.x * w0.w + hq.y * w1.w + hq.z * w2.w + hq.w * w3.w;
    }
    ((int2*)outp)[(size_t)g * 16 + sl] = h4_pack(o);
  }
}

extern "C" void kernel_launch(void* const* d_in, const int* in_sizes, int n_in,
                              void* d_out, int out_size, void* d_ws, size_t ws_size,
                              hipStream_t stream) {
  const float* x   = (const float*)d_in[0];
  const int*   ei  = (const int*)d_in[1];
  const float* ew  = (const float*)d_in[2];
  const float* W1  = (const float*)d_in[3];
  const float* b1  = (const float*)d_in[4];
  const float* Wh  = (const float*)d_in[5];
  const float* bh  = (const float*)d_in[6];
  const float* lw  = (const float*)d_in[7];
  const float* lb  = (const float*)d_in[8];
  float* out = (float*)d_out;

  const int* src = ei;            // edge_index[0] (message sources)
  const int* dst = ei + NEDGES;   // edge_index[1] (aggregation targets)

  // --- workspace layout; padded CSR if ws allows, else compact fallback ---
  const size_t capE = (size_t)NNODES * CAP;        // 4.8M padded slots
  const size_t needPadded =
      (size_t)NELEM * 2 * 2 + capE * 8 +
      ((size_t)NNODES * 3 + 1 + SCAN_NB) * 4;      // ~65 MB
  const bool padded = ws_size >= needPadded;
  const size_t nSlots = padded ? capE : (size_t)NEDGES;

  __half* A     = (__half*)d_ws;                     // N*64 fp16 (12.8 MB)
  __half* B     = A + (size_t)NELEM;                 // N*64 fp16 (12.8 MB)
  int2*  cpair  = (int2*)(B + (size_t)NELEM);        // padded: N*CAP, compact: E
  float* dinv   = (float*)(cpair + nSlots);          // N
  int*   cnt    = (int*)(dinv + (size_t)NNODES);     // N
  int*   rowptr = cnt + (size_t)NNODES;              // N+1 (compact only)
  int*   wptr   = rowptr + (size_t)NNODES + 1;       // N   (compact only)
  int*   bsum   = wptr + (size_t)NNODES;             // SCAN_NB (compact only)

  // dropout keys = jax.random.split(jax.random.key(42), 3), partitionable
  uint32_t dk[3][2];
  for (uint32_t i = 0; i < 3; ++i) tf2x32(0u, 42u, 0u, i, &dk[i][0], &dk[i][1]);

  const int gN = (NNODES + 255) / 256;
  const float* Wh0 = Wh;
  const float* Wh1 = Wh + (size_t)DH * DH;

  if (padded) {
    k_zero<<<gN, 256, 0, stream>>>(cnt);
    // 9375 blocks: 3125 GEMM (bid%3==2) + 6250 fill (bid%3 in {0,1})
    k_fill_gemm<<<3 * G_GEMM, 256, 0, stream>>>(src, dst, ew, cnt, cpair,
                                                x, W1, B, 0);
    k_degrow<1><<<G_GATH, 256, 0, stream>>>(rowptr, cnt, cpair, dinv);

    k_gg<0, 1><<<G_GATH, 256, 0, stream>>>(B, rowptr, cnt, cpair, dinv, b1,
                                           Wh0, lw, lb, A, dk[0][0], dk[0][1]);
    k_gg<0, 1><<<G_GATH, 256, 0, stream>>>(A, rowptr, cnt, cpair, dinv, bh,
                                           Wh1, lw, lb, B, dk[1][0], dk[1][1]);
    k_gg<1, 1><<<G_GATH, 256, 0, stream>>>(B, rowptr, cnt, cpair, dinv, bh + DH,
                                           nullptr, lw, lb, out, dk[2][0], dk[2][1]);
  } else {
    k_zero<<<gN, 256, 0, stream>>>(cnt);
    k_hist<<<G_EDGE, 256, 0, stream>>>(dst, cnt);
    k_scan1<<<SCAN_NB, SCAN_B, 0, stream>>>(cnt, rowptr, bsum);
    k_scan2<<<1, 128, 0, stream>>>(bsum);
    k_scan3<<<SCAN_NB, SCAN_B, 0, stream>>>(bsum, rowptr, wptr);
    k_fill_compact<<<G_EDGE, 256, 0, stream>>>(src, dst, ew, wptr, cpair);
    k_degrow<0><<<G_GATH, 256, 0, stream>>>(rowptr, cnt, cpair, dinv);
    k_fill_gemm<<<G_GEMM, 256, 0, stream>>>(src, dst, ew, cnt, nullptr,
                                            x, W1, B, 1);   // GEMM-only

    k_gg<0, 0><<<G_GATH, 256, 0, stream>>>(B, rowptr, cnt, cpair, dinv, b1,
                                           Wh0, lw, lb, A, dk[0][0], dk[0][1]);
    k_gg<0, 0><<<G_GATH, 256, 0, stream>>>(A, rowptr, cnt, cpair, dinv, bh,
                                           Wh1, lw, lb, B, dk[1][0], dk[1][1]);
    k_gg<1, 0><<<G_GATH, 256, 0, stream>>>(B, rowptr, cnt, cpair, dinv, bh + DH,
                                           nullptr, lw, lb, out, dk[2][0], dk[2][1]);
  }
}